// Round 4
// baseline (438.662 us; speedup 1.0000x reference)
//
#include <hip/hip_runtime.h>
#include <stdint.h>

typedef unsigned short u16;
typedef unsigned int u32;
typedef __bf16 bf16x8 __attribute__((ext_vector_type(8)));
typedef float floatx4 __attribute__((ext_vector_type(4)));

static __device__ __forceinline__ float bf2f(u16 u) {
  union { u32 i; float f; } v; v.i = ((u32)u) << 16; return v.f;
}
static __device__ __forceinline__ u16 f2bf(float f) {
  union { float f; u32 i; } v; v.f = f;
  u32 u = v.i;
  return (u16)((u + 0x7fffu + ((u >> 16) & 1u)) >> 16);  // RNE
}

// ---- edge dtype detector: int64 layout <=> odd int32 words are all high-halves (0) ----
__global__ void k_edgemode(const int* __restrict__ ei, int* __restrict__ flag) {
  int t = threadIdx.x;                       // 64 threads, 1 wave
  int v = ei[2 * t + 1];                     // odd positions among first 128 ints
  unsigned long long b = __ballot(v == 0);
  if (t == 0) *flag = (b == ~0ull) ? 1 : 0;  // all zero -> int64 buffer
}

static __device__ __forceinline__ int edge_src(const int* ei, int E, int i, int m64) {
  return m64 ? ei[2 * (size_t)i] : ei[i];
}
static __device__ __forceinline__ int edge_dst(const int* ei, int E, int i, int m64) {
  return m64 ? ei[2 * (size_t)E + 2 * (size_t)i] : ei[(size_t)E + i];
}

// ---- W transpose + fp32->bf16: Wt[n][k] = bf16(W[k][n]) ----
__global__ void k_transpose(const float* __restrict__ W1, const float* __restrict__ W2,
                            u16* __restrict__ Wt1, u16* __restrict__ Wt2) {
  int i = blockIdx.x * 256 + threadIdx.x;
  if (i < 256 * 128) {
    int k = i >> 7, c = i & 127;
    Wt1[c * 256 + k] = f2bf(W1[i]);
  } else {
    int j = i - 256 * 128;
    if (j < 128 * 64) {
      int k = j >> 6, c = j & 63;
      Wt2[c * 128 + k] = f2bf(W2[j]);
    }
  }
}

// ======== bucket partition: bucket b = dst>>7 (128 nodes per bucket) ========
#define CHUNK 2048

// per-chunk LDS histogram -> global bucket counts
__global__ void k_count(const int* __restrict__ ei, int E, const int* __restrict__ flag,
                        int* __restrict__ bucket_cnt, int NB) {
  __shared__ int h[1024];
  const int t = threadIdx.x;
  for (int i = t; i < 1024; i += 256) h[i] = 0;
  __syncthreads();
  const int c0 = blockIdx.x * CHUNK;
  const int cnt = min(CHUNK, E - c0);
  const int m64 = *flag;
  for (int i = t; i < cnt; i += 256)
    atomicAdd(&h[edge_dst(ei, E, c0 + i, m64) >> 7], 1);
  __syncthreads();
  for (int i = t; i < NB; i += 256)
    if (h[i]) atomicAdd(&bucket_cnt[i], h[i]);
}

// exclusive scan of bucket counts (single block, 256 thr x 4 entries)
__global__ void k_bscan(const int* __restrict__ bucket_cnt, int* __restrict__ bucket_base,
                        int* __restrict__ bucket_cursor, int NB,
                        int* __restrict__ row_ptr, int n, int E) {
  __shared__ int ts[256];
  const int t = threadIdx.x;
  const int b4 = t * 4;
  int a0 = (b4 + 0 < NB) ? bucket_cnt[b4 + 0] : 0;
  int a1 = (b4 + 1 < NB) ? bucket_cnt[b4 + 1] : 0;
  int a2 = (b4 + 2 < NB) ? bucket_cnt[b4 + 2] : 0;
  int a3 = (b4 + 3 < NB) ? bucket_cnt[b4 + 3] : 0;
  int p1 = a0, p2 = p1 + a1, p3 = p2 + a2, tsum = p3 + a3;
  ts[t] = tsum;
  __syncthreads();
  for (int off = 1; off < 256; off <<= 1) {
    int x = (t >= off) ? ts[t - off] : 0;
    __syncthreads();
    ts[t] += x;
    __syncthreads();
  }
  int ex0 = ts[t] - tsum;
  int e[4] = {ex0, ex0 + p1, ex0 + p2, ex0 + p3};
#pragma unroll
  for (int j = 0; j < 4; ++j) {
    int i = b4 + j;
    if (i < NB) { bucket_base[i] = e[j]; bucket_cursor[i] = e[j]; }
  }
  if (t == 0) row_ptr[n] = E;
}

// LDS-staged multi-split: stage chunk sorted by bucket, flush contiguous runs
__global__ void k_place(const int* __restrict__ ei, int E, const int* __restrict__ flag,
                        int* __restrict__ bucket_cursor, uint2* __restrict__ pairs, int NB) {
  __shared__ int h[1024];        // counts, then reused as global base per bucket
  __shared__ int ex[1024];       // exclusive local offsets (preserved)
  __shared__ int cur[1024];      // placement cursor
  __shared__ int ts[256];
  __shared__ uint2 stage[CHUNK];
  const int t = threadIdx.x;
  const int c0 = blockIdx.x * CHUNK;
  const int cnt = min(CHUNK, E - c0);
  const int m64 = *flag;

  for (int i = t; i < 1024; i += 256) h[i] = 0;
  __syncthreads();

  int es[8], ed[8];
#pragma unroll
  for (int j = 0; j < 8; ++j) {
    int i = t + j * 256;
    es[j] = 0; ed[j] = -1;
    if (i < cnt) {
      es[j] = edge_src(ei, E, c0 + i, m64);
      ed[j] = edge_dst(ei, E, c0 + i, m64);
      atomicAdd(&h[ed[j] >> 7], 1);
    }
  }
  __syncthreads();

  // scan h[0..1023] -> ex (exclusive), two-level
  const int b4 = t * 4;
  int a0 = h[b4], a1 = h[b4 + 1], a2 = h[b4 + 2], a3 = h[b4 + 3];
  int p1 = a0, p2 = p1 + a1, p3 = p2 + a2, tsum = p3 + a3;
  ts[t] = tsum;
  __syncthreads();
  for (int off = 1; off < 256; off <<= 1) {
    int x = (t >= off) ? ts[t - off] : 0;
    __syncthreads();
    ts[t] += x;
    __syncthreads();
  }
  int ex0 = ts[t] - tsum;
  ex[b4] = ex0;       cur[b4] = ex0;
  ex[b4 + 1] = ex0 + p1; cur[b4 + 1] = ex0 + p1;
  ex[b4 + 2] = ex0 + p2; cur[b4 + 2] = ex0 + p2;
  ex[b4 + 3] = ex0 + p3; cur[b4 + 3] = ex0 + p3;
  __syncthreads();

  // place into stage in bucket-sorted order
#pragma unroll
  for (int j = 0; j < 8; ++j) {
    if (ed[j] >= 0) {
      int b = ed[j] >> 7;
      int pos = atomicAdd(&cur[b], 1);
      stage[pos] = make_uint2((u32)es[j], (u32)ed[j]);
    }
  }
  // reserve global space per bucket (h[b] := global base)
  __syncthreads();
  for (int i = t; i < NB; i += 256) {
    int c = h[i];
    if (c > 0) h[i] = atomicAdd(&bucket_cursor[i], c);
  }
  __syncthreads();

  // flush: consecutive i within a bucket -> consecutive global positions
  for (int i = t; i < cnt; i += 256) {
    uint2 p = stage[i];
    int b = (int)(p.y >> 7);
    pairs[h[b] + (i - ex[b])] = p;
  }
}

// per-bucket exact CSR: row_ptr + coalesced srcs + dinv, all from LDS
#define BMAX 3072
__global__ void k_csr(const uint2* __restrict__ pairs, const int* __restrict__ bucket_cnt,
                      const int* __restrict__ bucket_base, int* __restrict__ row_ptr,
                      float* __restrict__ dinv, int* __restrict__ srcs, int n) {
  __shared__ int h[128], cur[128];
  __shared__ int lsrc[BMAX];
  const int b = blockIdx.x;
  const int t = threadIdx.x;
  const int cnt = bucket_cnt[b];
  const int base = bucket_base[b];

  if (t < 128) h[t] = 0;
  __syncthreads();
  for (int i = t; i < cnt; i += 256)
    atomicAdd(&h[pairs[base + i].y & 127], 1);
  __syncthreads();

  // scan 128 (inclusive -> exclusive), all threads hit barriers
  __shared__ int sc[128];
  int v = 0;
  if (t < 128) { v = h[t]; sc[t] = v; }
  __syncthreads();
  for (int off = 1; off < 128; off <<= 1) {
    int x = 0;
    if (t < 128 && t >= off) x = sc[t - off];
    __syncthreads();
    if (t < 128) sc[t] += x;
    __syncthreads();
  }
  if (t < 128) {
    int excl = sc[t] - v;
    cur[t] = excl;
    int node = b * 128 + t;
    if (node < n) {
      row_ptr[node] = base + excl;
      dinv[node] = rsqrtf(1.0f + (float)v);
    }
  }
  __syncthreads();

  for (int i = t; i < cnt; i += 256) {
    uint2 p = pairs[base + i];
    int pos = atomicAdd(&cur[p.y & 127], 1);
    if (pos < BMAX) lsrc[pos] = (int)p.x;
    else srcs[base + pos] = (int)p.x;   // overflow path (statistically never)
  }
  __syncthreads();
  const int lim = min(cnt, BMAX);
  for (int i = t; i < lim; i += 256) srcs[base + i] = lsrc[i];
}

// ---- direct-from-global MFMA GEMM: G[m][n] = bf16( (A @ Wt^T)[m][n] * dinv[m] ) ----
// No LDS, no barriers. 4 waves split N into quarters; each wave holds its whole
// B-slice in registers (KS*NT*4 VGPRs, read once from L2-resident Wt).
// A-fragments read straight from global: per (m-tile, kstep) a wave reads
// 16 rows x 128B (fp32) / 64B (bf16) contiguous -> fully coalesced, and with no
// barrier the compiler keeps many loads in flight (latency fix for round-3's
// 84us staging-bound gemm).
template<int N, int K, int MT, bool A_FP32>
__launch_bounds__(256, 2)
__global__ void k_gemm(const void* __restrict__ Ap, const u16* __restrict__ Wt,
                       const float* __restrict__ dinv, u16* __restrict__ G, int M)
{
  constexpr int KS = K / 32;                 // MFMA k-steps
  constexpr int NT = N / 64;                 // 16-wide n-tiles per wave (N split 4 ways)
  const int t = threadIdx.x;
  const int wave = t >> 6, lane = t & 63;
  const int lm = lane & 15, lq = lane >> 4;
  const int row0 = blockIdx.x * (MT * 16);
  const int colw = wave * (N / 4);

  // B slice -> registers (L2-hot after first blocks)
  bf16x8 bfr[KS][NT];
#pragma unroll
  for (int ks = 0; ks < KS; ++ks)
#pragma unroll
    for (int nt = 0; nt < NT; ++nt)
      bfr[ks][nt] = *(const bf16x8*)(Wt + (size_t)(colw + nt * 16 + lm) * K + ks * 32 + lq * 8);

  floatx4 acc[MT][NT];
#pragma unroll
  for (int mt = 0; mt < MT; ++mt)
#pragma unroll
    for (int nt = 0; nt < NT; ++nt) acc[mt][nt] = (floatx4)(0.0f);

#pragma unroll
  for (int ks = 0; ks < KS; ++ks) {
    bf16x8 afr[MT];
#pragma unroll
    for (int mt = 0; mt < MT; ++mt) {
      const int gr = row0 + mt * 16 + lm;
      const int kk = ks * 32 + lq * 8;
      if constexpr (A_FP32) {
        const float* A = (const float*)Ap;
        float4 v0 = make_float4(0.f, 0.f, 0.f, 0.f);
        float4 v1 = make_float4(0.f, 0.f, 0.f, 0.f);
        if (gr < M) {
          v0 = *(const float4*)(A + (size_t)gr * K + kk);
          v1 = *(const float4*)(A + (size_t)gr * K + kk + 4);
        }
        bf16x8 a;
        a[0] = (__bf16)v0.x; a[1] = (__bf16)v0.y; a[2] = (__bf16)v0.z; a[3] = (__bf16)v0.w;
        a[4] = (__bf16)v1.x; a[5] = (__bf16)v1.y; a[6] = (__bf16)v1.z; a[7] = (__bf16)v1.w;
        afr[mt] = a;
      } else {
        const u16* A = (const u16*)Ap;
        union { uint4 u; bf16x8 b; } cv;
        cv.u = make_uint4(0u, 0u, 0u, 0u);
        if (gr < M) cv.u = *(const uint4*)(A + (size_t)gr * K + kk);
        afr[mt] = cv.b;
      }
    }
#pragma unroll
    for (int mt = 0; mt < MT; ++mt)
#pragma unroll
      for (int nt = 0; nt < NT; ++nt)
        acc[mt][nt] = __builtin_amdgcn_mfma_f32_16x16x32_bf16(afr[mt], bfr[ks][nt],
                                                              acc[mt][nt], 0, 0, 0);
  }

  // C/D layout: row = (lane>>4)*4 + r, col = lane&15 (m89/m91-verified)
#pragma unroll
  for (int mt = 0; mt < MT; ++mt) {
    const int gr0 = row0 + mt * 16 + lq * 4;
#pragma unroll
    for (int nt = 0; nt < NT; ++nt) {
      const int gc = colw + nt * 16 + lm;
#pragma unroll
      for (int r = 0; r < 4; ++r) {
        const int gr = gr0 + r;
        if (gr < M) G[(size_t)gr * N + gc] = f2bf(acc[mt][nt][r] * dinv[gr]);
      }
    }
  }
}

// ---- gather aggregation: out[d] = act( dinv[d]*(sum_{s in N(d)} g[s] + g[d]) + bias ) ----
template<int F, bool RELU, bool OUT_BF16>
__global__ void k_agg(const u16* __restrict__ g, const int* __restrict__ row_ptr,
                      const int* __restrict__ srcs, const float* __restrict__ dinv,
                      const float* __restrict__ bias, void* __restrict__ outp, int n)
{
  const int node = blockIdx.x * 4 + (threadIdx.x >> 6);
  if (node >= n) return;
  const int lane = threadIdx.x & 63;
  constexpr int VPL = F / 64;
  const int col = lane * VPL;
  float a0 = 0.f, a1 = 0.f;

  if constexpr (VPL == 2) {                        // self contribution
    u32 v = *(const u32*)(g + (size_t)node * F + col);
    a0 += bf2f((u16)v); a1 += bf2f((u16)(v >> 16));
  } else {
    a0 += bf2f(g[(size_t)node * F + col]);
  }

  int e = row_ptr[node];
  const int e1 = row_ptr[node + 1];
  for (; e + 4 <= e1; e += 4) {                    // 4 independent gathers in flight
    int s0 = srcs[e], s1 = srcs[e + 1], s2 = srcs[e + 2], s3 = srcs[e + 3];
    if constexpr (VPL == 2) {
      u32 v0 = *(const u32*)(g + (size_t)s0 * F + col);
      u32 v1 = *(const u32*)(g + (size_t)s1 * F + col);
      u32 v2 = *(const u32*)(g + (size_t)s2 * F + col);
      u32 v3 = *(const u32*)(g + (size_t)s3 * F + col);
      a0 += bf2f((u16)v0) + bf2f((u16)v1) + bf2f((u16)v2) + bf2f((u16)v3);
      a1 += bf2f((u16)(v0 >> 16)) + bf2f((u16)(v1 >> 16)) +
            bf2f((u16)(v2 >> 16)) + bf2f((u16)(v3 >> 16));
    } else {
      float f0 = bf2f(g[(size_t)s0 * F + col]);
      float f1 = bf2f(g[(size_t)s1 * F + col]);
      float f2 = bf2f(g[(size_t)s2 * F + col]);
      float f3 = bf2f(g[(size_t)s3 * F + col]);
      a0 += f0 + f1 + f2 + f3;
    }
  }
  for (; e < e1; ++e) {
    int s0 = srcs[e];
    if constexpr (VPL == 2) {
      u32 v = *(const u32*)(g + (size_t)s0 * F + col);
      a0 += bf2f((u16)v); a1 += bf2f((u16)(v >> 16));
    } else {
      a0 += bf2f(g[(size_t)s0 * F + col]);
    }
  }

  const float dv = dinv[node];
  float o0 = dv * a0 + bias[col];
  if (RELU) o0 = fmaxf(o0, 0.f);
  float o1 = 0.f;
  if constexpr (VPL == 2) {
    o1 = dv * a1 + bias[col + 1];
    if (RELU) o1 = fmaxf(o1, 0.f);
  }

  if constexpr (OUT_BF16) {
    u16* out = (u16*)outp;
    if constexpr (VPL == 2) {
      u32 pk = (u32)f2bf(o0) | ((u32)f2bf(o1) << 16);
      *(u32*)(out + (size_t)node * F + col) = pk;
    } else {
      out[(size_t)node * F + col] = f2bf(o0);
    }
  } else {
    float* out = (float*)outp;
    if constexpr (VPL == 2) {
      *(float2*)(out + (size_t)node * F + col) = make_float2(o0, o1);
    } else {
      out[(size_t)node * F + col] = o0;
    }
  }
}

extern "C" void kernel_launch(void* const* d_in, const int* in_sizes, int n_in,
                              void* d_out, int out_size, void* d_ws, size_t ws_size,
                              hipStream_t stream)
{
  const float* x  = (const float*)d_in[0];   // [n,256] fp32
  const int*   ei = (const int*)d_in[1];     // [2,E] int32 (or int64 -- detected)
  const float* W1 = (const float*)d_in[2];   // [256,128] fp32
  const float* b1 = (const float*)d_in[3];   // [128] fp32
  const float* W2 = (const float*)d_in[4];   // [128,64] fp32
  const float* b2 = (const float*)d_in[5];   // [64] fp32

  const int n = in_sizes[0] / 256;
  const int E = in_sizes[1] / 2;
  const int NB = (n + 127) >> 7;             // buckets of 128 nodes (<=1024)

  char* ws = (char*)d_ws;
  size_t off = 0;
  auto alloc = [&](size_t bytes) -> void* {
    void* p = ws + off;
    off = (off + bytes + 255) & ~(size_t)255;
    return p;
  };
  int*   row_ptr = (int*)alloc((size_t)(n + 1) * 4);
  int*   bcnt    = (int*)alloc(1024 * 4);
  int*   bbase   = (int*)alloc(1024 * 4);
  int*   bcur    = (int*)alloc(1024 * 4);
  int*   eflag   = (int*)alloc(256);
  float* dinv    = (float*)alloc((size_t)n * 4);
  u16*   Wt1     = (u16*)alloc(256 * 128 * 2);
  u16*   Wt2     = (u16*)alloc(128 * 64 * 2);
  uint2* pairs   = (uint2*)alloc((size_t)E * 8);
  int*   srcs    = (int*)alloc((size_t)E * 4);
  u16*   g1      = (u16*)alloc((size_t)n * 128 * 2);
  u16*   y1      = (u16*)alloc((size_t)n * 128 * 2);
  u16*   g2      = (u16*)alloc((size_t)n * 64 * 2);
  (void)ws_size; (void)n_in; (void)out_size;

  const int TB = 256;
  const int nbC = (E + CHUNK - 1) / CHUNK;

  hipMemsetAsync(bcnt, 0, 1024 * 4, stream);
  k_edgemode<<<1, 64, 0, stream>>>(ei, eflag);
  k_transpose<<<(256 * 128 + 128 * 64 + TB - 1) / TB, TB, 0, stream>>>(W1, W2, Wt1, Wt2);
  k_count<<<nbC, TB, 0, stream>>>(ei, E, eflag, bcnt, NB);
  k_bscan<<<1, TB, 0, stream>>>(bcnt, bbase, bcur, NB, row_ptr, n, E);
  k_place<<<nbC, TB, 0, stream>>>(ei, E, eflag, bcur, pairs, NB);
  k_csr<<<NB, TB, 0, stream>>>(pairs, bcnt, bbase, row_ptr, dinv, srcs, n);

  k_gemm<128, 256, 4, true><<<(n + 63) / 64, 256, 0, stream>>>(x, Wt1, dinv, g1, n);
  k_agg<128, true, true><<<(n + 3) / 4, 256, 0, stream>>>(g1, row_ptr, srcs, dinv, b1, y1, n);
  k_gemm<64, 128, 4, false><<<(n + 63) / 64, 256, 0, stream>>>(y1, Wt2, dinv, g2, n);
  k_agg<64, false, false><<<(n + 3) / 4, 256, 0, stream>>>(g2, row_ptr, srcs, dinv, b2, d_out, n);
}

// Round 5
// 424.986 us; speedup vs baseline: 1.0322x; 1.0322x over previous
//
#include <hip/hip_runtime.h>
#include <stdint.h>

typedef unsigned short u16;
typedef unsigned int u32;
typedef __bf16 bf16x8 __attribute__((ext_vector_type(8)));
typedef float floatx4 __attribute__((ext_vector_type(4)));

static __device__ __forceinline__ float bf2f(u16 u) {
  union { u32 i; float f; } v; v.i = ((u32)u) << 16; return v.f;
}
static __device__ __forceinline__ u16 f2bf(float f) {
  union { float f; u32 i; } v; v.f = f;
  u32 u = v.i;
  return (u16)((u + 0x7fffu + ((u >> 16) & 1u)) >> 16);  // RNE
}

// async 16B/lane global->LDS DMA: lds dst = base + lane*16 (wave-uniform base)
static __device__ __forceinline__ void gload_lds16(const void* g, void* l) {
  __builtin_amdgcn_global_load_lds(
      (const __attribute__((address_space(1))) void*)g,
      (__attribute__((address_space(3))) void*)l, 16, 0, 0);
}

// ---- edge dtype detector: int64 layout <=> odd int32 words are all high-halves (0) ----
__global__ void k_edgemode(const int* __restrict__ ei, int* __restrict__ flag) {
  int t = threadIdx.x;                       // 64 threads, 1 wave
  int v = ei[2 * t + 1];                     // odd positions among first 128 ints
  unsigned long long b = __ballot(v == 0);
  if (t == 0) *flag = (b == ~0ull) ? 1 : 0;  // all zero -> int64 buffer
}

static __device__ __forceinline__ int edge_src(const int* ei, int E, int i, int m64) {
  return m64 ? ei[2 * (size_t)i] : ei[i];
}
static __device__ __forceinline__ int edge_dst(const int* ei, int E, int i, int m64) {
  return m64 ? ei[2 * (size_t)E + 2 * (size_t)i] : ei[(size_t)E + i];
}

// ---- W transpose + fp32->bf16: Wt[n][k] = bf16(W[k][n]) ----
__global__ void k_transpose(const float* __restrict__ W1, const float* __restrict__ W2,
                            u16* __restrict__ Wt1, u16* __restrict__ Wt2) {
  int i = blockIdx.x * 256 + threadIdx.x;
  if (i < 256 * 128) {
    int k = i >> 7, c = i & 127;
    Wt1[c * 256 + k] = f2bf(W1[i]);
  } else {
    int j = i - 256 * 128;
    if (j < 128 * 64) {
      int k = j >> 6, c = j & 63;
      Wt2[c * 128 + k] = f2bf(W2[j]);
    }
  }
}

// ======== bucket partition: bucket b = dst>>7 (128 nodes per bucket) ========
#define CHUNK 2048

// per-chunk LDS histogram -> global bucket counts
__global__ void k_count(const int* __restrict__ ei, int E, const int* __restrict__ flag,
                        int* __restrict__ bucket_cnt, int NB) {
  __shared__ int h[1024];
  const int t = threadIdx.x;
  for (int i = t; i < 1024; i += 256) h[i] = 0;
  __syncthreads();
  const int c0 = blockIdx.x * CHUNK;
  const int cnt = min(CHUNK, E - c0);
  const int m64 = *flag;
  for (int i = t; i < cnt; i += 256)
    atomicAdd(&h[edge_dst(ei, E, c0 + i, m64) >> 7], 1);
  __syncthreads();
  for (int i = t; i < NB; i += 256)
    if (h[i]) atomicAdd(&bucket_cnt[i], h[i]);
}

// exclusive scan of bucket counts (single block, 256 thr x 4 entries)
__global__ void k_bscan(const int* __restrict__ bucket_cnt, int* __restrict__ bucket_base,
                        int* __restrict__ bucket_cursor, int NB,
                        int* __restrict__ row_ptr, int n, int E) {
  __shared__ int ts[256];
  const int t = threadIdx.x;
  const int b4 = t * 4;
  int a0 = (b4 + 0 < NB) ? bucket_cnt[b4 + 0] : 0;
  int a1 = (b4 + 1 < NB) ? bucket_cnt[b4 + 1] : 0;
  int a2 = (b4 + 2 < NB) ? bucket_cnt[b4 + 2] : 0;
  int a3 = (b4 + 3 < NB) ? bucket_cnt[b4 + 3] : 0;
  int p1 = a0, p2 = p1 + a1, p3 = p2 + a2, tsum = p3 + a3;
  ts[t] = tsum;
  __syncthreads();
  for (int off = 1; off < 256; off <<= 1) {
    int x = (t >= off) ? ts[t - off] : 0;
    __syncthreads();
    ts[t] += x;
    __syncthreads();
  }
  int ex0 = ts[t] - tsum;
  int e[4] = {ex0, ex0 + p1, ex0 + p2, ex0 + p3};
#pragma unroll
  for (int j = 0; j < 4; ++j) {
    int i = b4 + j;
    if (i < NB) { bucket_base[i] = e[j]; bucket_cursor[i] = e[j]; }
  }
  if (t == 0) row_ptr[n] = E;
}

// LDS-staged multi-split: stage chunk sorted by bucket, flush contiguous runs
__global__ void k_place(const int* __restrict__ ei, int E, const int* __restrict__ flag,
                        int* __restrict__ bucket_cursor, uint2* __restrict__ pairs, int NB) {
  __shared__ int h[1024];        // counts, then reused as global base per bucket
  __shared__ int ex[1024];       // exclusive local offsets (preserved)
  __shared__ int cur[1024];      // placement cursor
  __shared__ int ts[256];
  __shared__ uint2 stage[CHUNK];
  const int t = threadIdx.x;
  const int c0 = blockIdx.x * CHUNK;
  const int cnt = min(CHUNK, E - c0);
  const int m64 = *flag;

  for (int i = t; i < 1024; i += 256) h[i] = 0;
  __syncthreads();

  int es[8], ed[8];
#pragma unroll
  for (int j = 0; j < 8; ++j) {
    int i = t + j * 256;
    es[j] = 0; ed[j] = -1;
    if (i < cnt) {
      es[j] = edge_src(ei, E, c0 + i, m64);
      ed[j] = edge_dst(ei, E, c0 + i, m64);
      atomicAdd(&h[ed[j] >> 7], 1);
    }
  }
  __syncthreads();

  // scan h[0..1023] -> ex (exclusive), two-level
  const int b4 = t * 4;
  int a0 = h[b4], a1 = h[b4 + 1], a2 = h[b4 + 2], a3 = h[b4 + 3];
  int p1 = a0, p2 = p1 + a1, p3 = p2 + a2, tsum = p3 + a3;
  ts[t] = tsum;
  __syncthreads();
  for (int off = 1; off < 256; off <<= 1) {
    int x = (t >= off) ? ts[t - off] : 0;
    __syncthreads();
    ts[t] += x;
    __syncthreads();
  }
  int ex0 = ts[t] - tsum;
  ex[b4] = ex0;       cur[b4] = ex0;
  ex[b4 + 1] = ex0 + p1; cur[b4 + 1] = ex0 + p1;
  ex[b4 + 2] = ex0 + p2; cur[b4 + 2] = ex0 + p2;
  ex[b4 + 3] = ex0 + p3; cur[b4 + 3] = ex0 + p3;
  __syncthreads();

  // place into stage in bucket-sorted order
#pragma unroll
  for (int j = 0; j < 8; ++j) {
    if (ed[j] >= 0) {
      int b = ed[j] >> 7;
      int pos = atomicAdd(&cur[b], 1);
      stage[pos] = make_uint2((u32)es[j], (u32)ed[j]);
    }
  }
  // reserve global space per bucket (h[b] := global base)
  __syncthreads();
  for (int i = t; i < NB; i += 256) {
    int c = h[i];
    if (c > 0) h[i] = atomicAdd(&bucket_cursor[i], c);
  }
  __syncthreads();

  // flush: consecutive i within a bucket -> consecutive global positions
  for (int i = t; i < cnt; i += 256) {
    uint2 p = stage[i];
    int b = (int)(p.y >> 7);
    pairs[h[b] + (i - ex[b])] = p;
  }
}

// per-bucket exact CSR: row_ptr + coalesced srcs + dinv, all from LDS
#define BMAX 3072
__global__ void k_csr(const uint2* __restrict__ pairs, const int* __restrict__ bucket_cnt,
                      const int* __restrict__ bucket_base, int* __restrict__ row_ptr,
                      float* __restrict__ dinv, int* __restrict__ srcs, int n) {
  __shared__ int h[128], cur[128];
  __shared__ int lsrc[BMAX];
  const int b = blockIdx.x;
  const int t = threadIdx.x;
  const int cnt = bucket_cnt[b];
  const int base = bucket_base[b];

  if (t < 128) h[t] = 0;
  __syncthreads();
  for (int i = t; i < cnt; i += 256)
    atomicAdd(&h[pairs[base + i].y & 127], 1);
  __syncthreads();

  // scan 128 (inclusive -> exclusive), all threads hit barriers
  __shared__ int sc[128];
  int v = 0;
  if (t < 128) { v = h[t]; sc[t] = v; }
  __syncthreads();
  for (int off = 1; off < 128; off <<= 1) {
    int x = 0;
    if (t < 128 && t >= off) x = sc[t - off];
    __syncthreads();
    if (t < 128) sc[t] += x;
    __syncthreads();
  }
  if (t < 128) {
    int excl = sc[t] - v;
    cur[t] = excl;
    int node = b * 128 + t;
    if (node < n) {
      row_ptr[node] = base + excl;
      dinv[node] = rsqrtf(1.0f + (float)v);
    }
  }
  __syncthreads();

  for (int i = t; i < cnt; i += 256) {
    uint2 p = pairs[base + i];
    int pos = atomicAdd(&cur[p.y & 127], 1);
    if (pos < BMAX) lsrc[pos] = (int)p.x;
    else srcs[base + pos] = (int)p.x;   // overflow path (statistically never)
  }
  __syncthreads();
  const int lim = min(cnt, BMAX);
  for (int i = t; i < lim; i += 256) srcs[base + i] = lsrc[i];
}

// ---- MFMA GEMM with global_load_lds staging ----
// G[m][n] = bf16( (A @ Wt^T)[m][n] * dinv[m] ).  Block = 64 rows x N cols,
// 4 waves in a 2x2 grid (wave tile 32 x N/2).  A staged to LDS via async DMA
// (16B/lane, no VGPR destinations -> deep load queue; fixes round-4's ~8
// loads-in-flight register starvation).  1KB per issue + 16B pad per issue
// group.  fp32->bf16 conversion happens at the LDS->register fragment read.
template<int N, int K, bool A_FP32>
__launch_bounds__(256, 2)
__global__ void k_gemm(const void* __restrict__ Ap, const u16* __restrict__ Wt,
                       const float* __restrict__ dinv, u16* __restrict__ G, int M)
{
  constexpr int ESZ = A_FP32 ? 4 : 2;
  constexpr int BPR = K * ESZ;               // bytes per A row (1024 fp32 / 256 bf16)
  constexpr int RPI = 1024 / BPR;            // rows per 1KB DMA issue
  constexpr int NISS = 64 / RPI;             // issues per block
  constexpr int STRIDE = 1024 + 16;          // pad breaks power-of-2 bank stride
  __shared__ char lds[NISS * STRIDE];
  const int t = threadIdx.x;
  const int wave = t >> 6, lane = t & 63;
  const int row0 = blockIdx.x * 64;

  // stage 64 A rows -> LDS, all issues in flight before the single barrier
  constexpr int IPW = NISS / 4;              // issues per wave
#pragma unroll
  for (int i = 0; i < IPW; ++i) {
    const int g = wave * IPW + i;
    int r0 = row0 + g * RPI;
    if (r0 < M) {
      if (r0 > M - RPI) r0 = M - RPI;        // clamp (M % RPI == 0 here)
      gload_lds16((const char*)Ap + (size_t)r0 * BPR + lane * 16, lds + g * STRIDE);
    }
  }
  __syncthreads();

  const int wr = wave >> 1, wc = wave & 1;   // 2x2 wave grid
  constexpr int NT = N / 32;                 // 16-wide n-tiles per wave (N/2 cols)
  constexpr int KS = K / 32;
  const int lm = lane & 15, lq = lane >> 4;

  floatx4 acc[2][NT];
#pragma unroll
  for (int i = 0; i < 2; ++i)
#pragma unroll
    for (int j = 0; j < NT; ++j) acc[i][j] = (floatx4)(0.0f);

  const int arow = wr * 32 + lm;             // A row for m-tile 0 (m-tile 1: +16)
  const int brow0 = wc * (N / 2) + lm;

#pragma unroll
  for (int ks = 0; ks < KS; ++ks) {
    bf16x8 a[2];
#pragma unroll
    for (int mt = 0; mt < 2; ++mt) {
      const int r = arow + mt * 16;
      const char* p = lds + (r / RPI) * STRIDE + (r % RPI) * BPR + (ks * 32 + lq * 8) * ESZ;
      if constexpr (A_FP32) {
        float4 f0 = *(const float4*)p;
        float4 f1 = *(const float4*)(p + 16);
        bf16x8 av;
        av[0] = (__bf16)f0.x; av[1] = (__bf16)f0.y; av[2] = (__bf16)f0.z; av[3] = (__bf16)f0.w;
        av[4] = (__bf16)f1.x; av[5] = (__bf16)f1.y; av[6] = (__bf16)f1.z; av[7] = (__bf16)f1.w;
        a[mt] = av;
      } else {
        a[mt] = *(const bf16x8*)p;
      }
    }
    bf16x8 b[NT];
#pragma unroll
    for (int nt = 0; nt < NT; ++nt)
      b[nt] = *(const bf16x8*)(Wt + (size_t)(brow0 + nt * 16) * K + ks * 32 + lq * 8);
#pragma unroll
    for (int nt = 0; nt < NT; ++nt) {
      acc[0][nt] = __builtin_amdgcn_mfma_f32_16x16x32_bf16(a[0], b[nt], acc[0][nt], 0, 0, 0);
      acc[1][nt] = __builtin_amdgcn_mfma_f32_16x16x32_bf16(a[1], b[nt], acc[1][nt], 0, 0, 0);
    }
  }

  // C/D layout: row = (lane>>4)*4 + r, col = lane&15 (m89/m91-verified)
  const int crow0 = row0 + wr * 32 + lq * 4;
#pragma unroll
  for (int mt = 0; mt < 2; ++mt) {
#pragma unroll
    for (int nt = 0; nt < NT; ++nt) {
      const int gc = wc * (N / 2) + nt * 16 + lm;
#pragma unroll
      for (int r = 0; r < 4; ++r) {
        const int gr = crow0 + mt * 16 + r;
        if (gr < M) G[(size_t)gr * N + gc] = f2bf(acc[mt][nt][r] * dinv[gr]);
      }
    }
  }
}

// ---- gather aggregation: out[d] = act( dinv[d]*(sum_{s in N(d)} g[s] + g[d]) + bias ) ----
// one wave per node; fp32 register accumulation, no atomics; 8 gathers in flight.
template<int F, bool RELU, bool OUT_BF16>
__global__ void k_agg(const u16* __restrict__ g, const int* __restrict__ row_ptr,
                      const int* __restrict__ srcs, const float* __restrict__ dinv,
                      const float* __restrict__ bias, void* __restrict__ outp, int n)
{
  const int node = blockIdx.x * 4 + (threadIdx.x >> 6);
  if (node >= n) return;
  const int lane = threadIdx.x & 63;
  constexpr int VPL = F / 64;
  const int col = lane * VPL;
  float a0 = 0.f, a1 = 0.f;

  if constexpr (VPL == 2) {                        // self contribution
    u32 v = *(const u32*)(g + (size_t)node * F + col);
    a0 += bf2f((u16)v); a1 += bf2f((u16)(v >> 16));
  } else {
    a0 += bf2f(g[(size_t)node * F + col]);
  }

  int e = row_ptr[node];
  const int e1 = row_ptr[node + 1];
  for (; e + 8 <= e1; e += 8) {                    // 8 independent gathers in flight
    int s[8];
#pragma unroll
    for (int j = 0; j < 8; ++j) s[j] = srcs[e + j];
    if constexpr (VPL == 2) {
      u32 v[8];
#pragma unroll
      for (int j = 0; j < 8; ++j) v[j] = *(const u32*)(g + (size_t)s[j] * F + col);
#pragma unroll
      for (int j = 0; j < 8; ++j) {
        a0 += bf2f((u16)v[j]);
        a1 += bf2f((u16)(v[j] >> 16));
      }
    } else {
      float f[8];
#pragma unroll
      for (int j = 0; j < 8; ++j) f[j] = bf2f(g[(size_t)s[j] * F + col]);
#pragma unroll
      for (int j = 0; j < 8; ++j) a0 += f[j];
    }
  }
  for (; e < e1; ++e) {
    int s0 = srcs[e];
    if constexpr (VPL == 2) {
      u32 v = *(const u32*)(g + (size_t)s0 * F + col);
      a0 += bf2f((u16)v); a1 += bf2f((u16)(v >> 16));
    } else {
      a0 += bf2f(g[(size_t)s0 * F + col]);
    }
  }

  const float dv = dinv[node];
  float o0 = dv * a0 + bias[col];
  if (RELU) o0 = fmaxf(o0, 0.f);
  float o1 = 0.f;
  if constexpr (VPL == 2) {
    o1 = dv * a1 + bias[col + 1];
    if (RELU) o1 = fmaxf(o1, 0.f);
  }

  if constexpr (OUT_BF16) {
    u16* out = (u16*)outp;
    if constexpr (VPL == 2) {
      u32 pk = (u32)f2bf(o0) | ((u32)f2bf(o1) << 16);
      *(u32*)(out + (size_t)node * F + col) = pk;
    } else {
      out[(size_t)node * F + col] = f2bf(o0);
    }
  } else {
    float* out = (float*)outp;
    if constexpr (VPL == 2) {
      *(float2*)(out + (size_t)node * F + col) = make_float2(o0, o1);
    } else {
      out[(size_t)node * F + col] = o0;
    }
  }
}

extern "C" void kernel_launch(void* const* d_in, const int* in_sizes, int n_in,
                              void* d_out, int out_size, void* d_ws, size_t ws_size,
                              hipStream_t stream)
{
  const float* x  = (const float*)d_in[0];   // [n,256] fp32
  const int*   ei = (const int*)d_in[1];     // [2,E] int32 (or int64 -- detected)
  const float* W1 = (const float*)d_in[2];   // [256,128] fp32
  const float* b1 = (const float*)d_in[3];   // [128] fp32
  const float* W2 = (const float*)d_in[4];   // [128,64] fp32
  const float* b2 = (const float*)d_in[5];   // [64] fp32

  const int n = in_sizes[0] / 256;
  const int E = in_sizes[1] / 2;
  const int NB = (n + 127) >> 7;             // buckets of 128 nodes (<=1024)

  char* ws = (char*)d_ws;
  size_t off = 0;
  auto alloc = [&](size_t bytes) -> void* {
    void* p = ws + off;
    off = (off + bytes + 255) & ~(size_t)255;
    return p;
  };
  int*   row_ptr = (int*)alloc((size_t)(n + 1) * 4);
  int*   bcnt    = (int*)alloc(1024 * 4);
  int*   bbase   = (int*)alloc(1024 * 4);
  int*   bcur    = (int*)alloc(1024 * 4);
  int*   eflag   = (int*)alloc(256);
  float* dinv    = (float*)alloc((size_t)n * 4);
  u16*   Wt1     = (u16*)alloc(256 * 128 * 2);
  u16*   Wt2     = (u16*)alloc(128 * 64 * 2);
  uint2* pairs   = (uint2*)alloc((size_t)E * 8);
  int*   srcs    = (int*)alloc((size_t)E * 4);
  u16*   g1      = (u16*)alloc((size_t)n * 128 * 2);
  u16*   y1      = (u16*)alloc((size_t)n * 128 * 2);
  u16*   g2      = (u16*)alloc((size_t)n * 64 * 2);
  (void)ws_size; (void)n_in; (void)out_size;

  const int TB = 256;
  const int nbC = (E + CHUNK - 1) / CHUNK;

  hipMemsetAsync(bcnt, 0, 1024 * 4, stream);
  k_edgemode<<<1, 64, 0, stream>>>(ei, eflag);
  k_transpose<<<(256 * 128 + 128 * 64 + TB - 1) / TB, TB, 0, stream>>>(W1, W2, Wt1, Wt2);
  k_count<<<nbC, TB, 0, stream>>>(ei, E, eflag, bcnt, NB);
  k_bscan<<<1, TB, 0, stream>>>(bcnt, bbase, bcur, NB, row_ptr, n, E);
  k_place<<<nbC, TB, 0, stream>>>(ei, E, eflag, bcur, pairs, NB);
  k_csr<<<NB, TB, 0, stream>>>(pairs, bcnt, bbase, row_ptr, dinv, srcs, n);

  k_gemm<128, 256, true><<<(n + 63) / 64, 256, 0, stream>>>(x, Wt1, dinv, g1, n);
  k_agg<128, true, true><<<(n + 3) / 4, 256, 0, stream>>>(g1, row_ptr, srcs, dinv, b1, y1, n);
  k_gemm<64, 128, false><<<(n + 63) / 64, 256, 0, stream>>>(y1, Wt2, dinv, g2, n);
  k_agg<64, false, false><<<(n + 3) / 4, 256, 0, stream>>>(g2, row_ptr, srcs, dinv, b2, d_out, n);
}